// Round 12
// baseline (466.049 us; speedup 1.0000x reference)
//
#include <hip/hip_runtime.h>
#include <hip/hip_fp16.h>

// Problem constants (match reference)
#define N_NODES 50000
#define N_EDGES 800000
#define F_IN 128
#define H1 100
#define H2 200
#define F_OUT 16
#define CAP 64     // fixed CSR slots/node: deg ~ Binom(800k,1/50k) = 16 +/- 4; P(>64) ~ 1e-20
#define NXCD 8
#define DRANGE (N_NODES / NXCD)  // 6250 destination nodes per XCD partition

typedef _Float16 f16x8 __attribute__((ext_vector_type(8)));
typedef _Float16 f16x4 __attribute__((ext_vector_type(4)));
typedef float f32x4 __attribute__((ext_vector_type(4)));

// ---------------- XCC-pinned fused CSR build with work-stealing ----------------
// Each block reads its REAL XCD id (HW_REG_XCC_ID, verified on gfx950) and
// serves that XCD's destination-range queue via an atomic ticket; once drained
// it steals from the other queues. Correctness is independent of any
// blockIdx->XCD mapping assumption; locality is best-effort-optimal: all
// blocks resident on XCD k scatter into k's 0.8 MB csrf slice + 25 KB cnt
// slice, which are L2-resident. Each of the 8 queues scans the full edge list
// (8x 6.4 MB sequential L3-resident reads). cnt keeps TRUE degree.

__global__ void count_fill_kernel(const int* __restrict__ col, const int* __restrict__ row,
                                  int* __restrict__ cnt, unsigned short* __restrict__ csrf,
                                  int* __restrict__ tickets,
                                  int n_edges, int chunk, int nchunk) {
    unsigned xcc;
    asm volatile("s_getreg_b32 %0, hwreg(HW_REG_XCC_ID)" : "=s"(xcc));
    int d = (int)(xcc & 7);
    __shared__ int s_t;
    for (int dd = 0; dd < NXCD; ++dd) {
        int q = (d + dd) & 7;              // own queue first, then steal
        int lo = q * DRANGE, hi = lo + DRANGE;
        for (;;) {
            if (threadIdx.x == 0) s_t = atomicAdd(&tickets[q], 1);
            __syncthreads();
            int t = s_t;
            __syncthreads();               // protect s_t before next grab
            if (t >= nchunk) break;
            int base = t * chunk;
            int end = min(base + chunk, n_edges);
            for (int e = base + (int)threadIdx.x; e < end; e += blockDim.x) {
                int c = col[e];
                if (c >= lo && c < hi) {
                    int r = atomicAdd(&cnt[c], 1);
                    if (r < CAP) csrf[(size_t)c * CAP + r] = (unsigned short)row[e];
                }
            }
        }
    }
}

// ---------------- MFMA fp16 GEMM layer 1 (f32 accumulate), fp16 out pitch 104 ----
// y1s[n][c] = (f16)( (sum_k x[n][k] W1[k][c]) * rsqrt(cnt[n]+1) ), c<100
// Block: 4 waves, BM=128 rows, 7 n-frags (112 virtual cols). BK=32.
// LDS: As [128][40] f16 row-major; Bs TRANSPOSED [112][40] f16.
// Frag maps (verified rounds 8-11): A row=lane&15,k=(lane>>4)*8+j;
// B col=lane&15 (from transposed Bs); D col=lane&15,row=(lane>>4)*4+reg.

__global__ __launch_bounds__(256) void gemm1_kernel(
        const float* __restrict__ A, const float* __restrict__ W,
        const int* __restrict__ cnt, _Float16* __restrict__ out, int n_rows) {
    constexpr int BM = 128, BK = 32, PIT = 40, K = F_IN, LDW = H1;
    __shared__ _Float16 As[BM * PIT];
    __shared__ _Float16 Bs[112 * PIT];

    int tid = threadIdx.x;
    int w = tid >> 6, lane = tid & 63;
    int lrow = lane & 15, lk = lane >> 4;
    int m0 = blockIdx.x * BM;

    f32x4 acc[2][7];
#pragma unroll
    for (int m = 0; m < 2; ++m)
#pragma unroll
        for (int nf = 0; nf < 7; ++nf) acc[m][nf] = (f32x4){0.f, 0.f, 0.f, 0.f};

    for (int kc = 0; kc < K; kc += BK) {
        __syncthreads();
        for (int i = tid; i < BM * 8; i += 256) {
            int r = i >> 3, q = i & 7;
            float4 v = make_float4(0.f, 0.f, 0.f, 0.f);
            if (m0 + r < n_rows) v = *(const float4*)&A[(size_t)(m0 + r) * K + kc + q * 4];
            f16x4 h = {(_Float16)v.x, (_Float16)v.y, (_Float16)v.z, (_Float16)v.w};
            *(f16x4*)&As[r * PIT + q * 4] = h;
        }
        for (int i = tid; i < 112 * BK; i += 256) {
            int k = i / 112, c = i - k * 112;
            float v = (c < LDW) ? W[(size_t)(kc + k) * LDW + c] : 0.f;
            Bs[c * PIT + k] = (_Float16)v;
        }
        __syncthreads();
        f16x8 a0 = *(const f16x8*)&As[(w * 32 + lrow) * PIT + lk * 8];
        f16x8 a1 = *(const f16x8*)&As[(w * 32 + 16 + lrow) * PIT + lk * 8];
#pragma unroll
        for (int nf = 0; nf < 7; ++nf) {
            f16x8 b = *(const f16x8*)&Bs[(nf * 16 + lrow) * PIT + lk * 8];
            acc[0][nf] = __builtin_amdgcn_mfma_f32_16x16x32_f16(a0, b, acc[0][nf], 0, 0, 0);
            acc[1][nf] = __builtin_amdgcn_mfma_f32_16x16x32_f16(a1, b, acc[1][nf], 0, 0, 0);
        }
    }

#pragma unroll
    for (int m = 0; m < 2; ++m) {
        int rb = m0 + w * 32 + m * 16 + lk * 4;
#pragma unroll
        for (int r = 0; r < 4; ++r) {
            int grow = rb + r;
            if (grow >= n_rows) continue;
            float d = rsqrtf((float)cnt[grow] + 1.0f);
            size_t base = (size_t)grow * 104;
#pragma unroll
            for (int nf = 0; nf < 7; ++nf) {
                int c = nf * 16 + lrow;
                if (c < 100) out[base + c] = (_Float16)(acc[m][nf][r] * d);
            }
        }
    }
}

// ---------------- MFMA fp16 GEMM layer 2 (f16 input pitch 104), 2 col-planes ----
// h2[plane(by)][n][c] = (f16) relu( sum_k g2h[n][k] W2[k][col_off+c] + b2[col_off+c] )

__global__ __launch_bounds__(256) void gemm2_kernel(
        const _Float16* __restrict__ A, const float* __restrict__ W,
        const float* __restrict__ b2, _Float16* __restrict__ out,
        size_t planeH, int n_rows) {
    constexpr int BM = 128, BK = 32, PIT = 40, K = H1, LDW = H2;
    __shared__ _Float16 As[BM * PIT];
    __shared__ _Float16 Bs[112 * PIT];

    int tid = threadIdx.x;
    int w = tid >> 6, lane = tid & 63;
    int lrow = lane & 15, lk = lane >> 4;
    int m0 = blockIdx.x * BM;
    int col_off = blockIdx.y * 100;

    f32x4 acc[2][7];
#pragma unroll
    for (int m = 0; m < 2; ++m)
#pragma unroll
        for (int nf = 0; nf < 7; ++nf) acc[m][nf] = (f32x4){0.f, 0.f, 0.f, 0.f};

    for (int kc = 0; kc < K; kc += BK) {  // 0,32,64,96
        __syncthreads();
        // A: f16 pitch 104; zero k>=100 tail
        for (int i = tid; i < BM * 8; i += 256) {
            int r = i >> 3, q = i & 7, kb = kc + q * 4;
            f16x4 h = {(_Float16)0.f, (_Float16)0.f, (_Float16)0.f, (_Float16)0.f};
            if (m0 + r < n_rows && kb < K)
                h = *(const f16x4*)&A[(size_t)(m0 + r) * 104 + kb];
            *(f16x4*)&As[r * PIT + q * 4] = h;
        }
        // B transposed: 112 virtual cols of this plane; zero c>=100 / k>=100
        for (int i = tid; i < 112 * BK; i += 256) {
            int k = i / 112, c = i - k * 112;
            float v = (c < 100 && kc + k < K) ? W[(size_t)(kc + k) * LDW + col_off + c] : 0.f;
            Bs[c * PIT + k] = (_Float16)v;
        }
        __syncthreads();
        f16x8 a0 = *(const f16x8*)&As[(w * 32 + lrow) * PIT + lk * 8];
        f16x8 a1 = *(const f16x8*)&As[(w * 32 + 16 + lrow) * PIT + lk * 8];
#pragma unroll
        for (int nf = 0; nf < 7; ++nf) {
            f16x8 b = *(const f16x8*)&Bs[(nf * 16 + lrow) * PIT + lk * 8];
            acc[0][nf] = __builtin_amdgcn_mfma_f32_16x16x32_f16(a0, b, acc[0][nf], 0, 0, 0);
            acc[1][nf] = __builtin_amdgcn_mfma_f32_16x16x32_f16(a1, b, acc[1][nf], 0, 0, 0);
        }
    }

    _Float16* o = out + blockIdx.y * planeH;
    float bv[7];
#pragma unroll
    for (int nf = 0; nf < 7; ++nf) {
        int c = nf * 16 + lrow;
        bv[nf] = (c < 100) ? b2[col_off + c] : 0.f;
    }
#pragma unroll
    for (int m = 0; m < 2; ++m) {
        int rb = m0 + w * 32 + m * 16 + lk * 4;
#pragma unroll
        for (int r = 0; r < 4; ++r) {
            int grow = rb + r;
            if (grow >= n_rows) continue;
            size_t base = (size_t)grow * 104;
#pragma unroll
            for (int nf = 0; nf < 7; ++nf) {
                int c = nf * 16 + lrow;
                if (c < 100) o[base + c] = (_Float16)fmaxf(acc[m][nf][r] + bv[nf], 0.f);
            }
        }
    }
}

// ---------------- Aggregation over fp16 rows (pitch 52 half2, one wave/node) ----
// acc[n] = Y[n] + sum_{src} Y[src]  (f32 accumulate); d = rsqrt(cnt[n]+1)
// L1=true : out[n] = f16( relu(d*acc + b) * d )   (h1s)
// L1=false: out[n] = f16( d*acc )                 (g2h)
// 8 gathers in flight (deg mean 16 -> two full batches). Slots are u16.

template <bool L1>
__global__ void agg_h_kernel(const __half2* __restrict__ Y, const int* __restrict__ cnt,
                             const unsigned short* __restrict__ csrf,
                             const float* __restrict__ bias,
                             __half2* __restrict__ out, int n_nodes) {
    int wave = threadIdx.x >> 6, lane = threadIdx.x & 63;
    int n = blockIdx.x * 4 + wave;
    if (n >= n_nodes) return;
    bool act = lane < 50;
    float ax = 0.f, ay = 0.f;
    if (act) {
        float2 v = __half22float2(Y[(size_t)n * 52 + lane]);  // self-loop term
        ax = v.x; ay = v.y;
    }
    int deg0 = cnt[n];
    int deg = min(deg0, CAP);
    const unsigned short* slots = csrf + (size_t)n * CAP;
    int my = (lane < deg) ? (int)slots[lane] : 0;  // one coalesced batch covers deg<=64
    int i = 0;
    for (; i + 8 <= deg; i += 8) {
        int s0 = __shfl(my, i),     s1 = __shfl(my, i + 1);
        int s2 = __shfl(my, i + 2), s3 = __shfl(my, i + 3);
        int s4 = __shfl(my, i + 4), s5 = __shfl(my, i + 5);
        int s6 = __shfl(my, i + 6), s7 = __shfl(my, i + 7);
        if (act) {
            float2 v0 = __half22float2(Y[(size_t)s0 * 52 + lane]);
            float2 v1 = __half22float2(Y[(size_t)s1 * 52 + lane]);
            float2 v2 = __half22float2(Y[(size_t)s2 * 52 + lane]);
            float2 v3 = __half22float2(Y[(size_t)s3 * 52 + lane]);
            float2 v4 = __half22float2(Y[(size_t)s4 * 52 + lane]);
            float2 v5 = __half22float2(Y[(size_t)s5 * 52 + lane]);
            float2 v6 = __half22float2(Y[(size_t)s6 * 52 + lane]);
            float2 v7 = __half22float2(Y[(size_t)s7 * 52 + lane]);
            ax += ((v0.x + v1.x) + (v2.x + v3.x)) + ((v4.x + v5.x) + (v6.x + v7.x));
            ay += ((v0.y + v1.y) + (v2.y + v3.y)) + ((v4.y + v5.y) + (v6.y + v7.y));
        }
    }
    for (; i + 4 <= deg; i += 4) {
        int s0 = __shfl(my, i),     s1 = __shfl(my, i + 1);
        int s2 = __shfl(my, i + 2), s3 = __shfl(my, i + 3);
        if (act) {
            float2 v0 = __half22float2(Y[(size_t)s0 * 52 + lane]);
            float2 v1 = __half22float2(Y[(size_t)s1 * 52 + lane]);
            float2 v2 = __half22float2(Y[(size_t)s2 * 52 + lane]);
            float2 v3 = __half22float2(Y[(size_t)s3 * 52 + lane]);
            ax += (v0.x + v1.x) + (v2.x + v3.x);
            ay += (v0.y + v1.y) + (v2.y + v3.y);
        }
    }
    for (; i < deg; ++i) {
        int s = __shfl(my, i);
        if (act) {
            float2 v = __half22float2(Y[(size_t)s * 52 + lane]);
            ax += v.x; ay += v.y;
        }
    }
    if (act) {
        float d = rsqrtf((float)deg0 + 1.0f);
        float ox, oy;
        if (L1) {
            int f = lane * 2;
            ox = fmaxf(fmaf(ax, d, bias[f]), 0.f) * d;
            oy = fmaxf(fmaf(ay, d, bias[f + 1]), 0.f) * d;
        } else {
            ox = ax * d;
            oy = ay * d;
        }
        out[(size_t)n * 52 + lane] = __float22half2_rn(make_float2(ox, oy));
    }
}

// ---------------- Final FC from fp16 h2 col-planes ----------------
// out[n][c] = sum_p sum_k h2[p][n][k] * Wfc[p*100+k][c] + bfc[c]

__global__ void fc_h_kernel(const __half2* __restrict__ h2, size_t plane2,
                            const float* __restrict__ W, const float* __restrict__ b,
                            float* __restrict__ out, int n_rows) {
    int idx = blockIdx.x * blockDim.x + threadIdx.x;
    int n = idx >> 2;
    int cg = (idx & 3) * 4;
    if (n >= n_rows) return;
    float a0 = 0.f, a1 = 0.f, a2 = 0.f, a3 = 0.f;
#pragma unroll
    for (int p = 0; p < 2; ++p) {
        const __half2* hr = h2 + p * plane2 + (size_t)n * 52;
        const float* Wp = W + (size_t)(p * 100) * F_OUT + cg;
#pragma unroll 5
        for (int k2 = 0; k2 < 50; ++k2) {
            float2 hv = __half22float2(hr[k2]);
            float4 w0 = *(const float4*)&Wp[(2 * k2) * F_OUT];
            float4 w1 = *(const float4*)&Wp[(2 * k2 + 1) * F_OUT];
            a0 = fmaf(hv.x, w0.x, fmaf(hv.y, w1.x, a0));
            a1 = fmaf(hv.x, w0.y, fmaf(hv.y, w1.y, a1));
            a2 = fmaf(hv.x, w0.z, fmaf(hv.y, w1.z, a2));
            a3 = fmaf(hv.x, w0.w, fmaf(hv.y, w1.w, a3));
        }
    }
    float4 bv = *(const float4*)&b[cg];
    float4 o = {a0 + bv.x, a1 + bv.y, a2 + bv.z, a3 + bv.w};
    *(float4*)&out[(size_t)n * F_OUT + cg] = o;
}

// ---------------- Launch ----------------

extern "C" void kernel_launch(void* const* d_in, const int* in_sizes, int n_in,
                              void* d_out, int out_size, void* d_ws, size_t ws_size,
                              hipStream_t stream) {
    const float* x   = (const float*)d_in[0];
    const int*   ei  = (const int*)d_in[1];
    const float* W1  = (const float*)d_in[2];
    const float* b1  = (const float*)d_in[3];
    const float* W2  = (const float*)d_in[4];
    const float* b2  = (const float*)d_in[5];
    const float* Wfc = (const float*)d_in[6];
    const float* bfc = (const float*)d_in[7];
    float* out = (float*)d_out;

    const int N = N_NODES, E = N_EDGES;
    const int* row = ei;
    const int* col = ei + E;

    // Workspace (~38 MB, all 16B-aligned)
    char* ws = (char*)d_ws;
    int*            cnt     = (int*)ws;             ws += (size_t)N * 4;        // true in-degree
    int*            tickets = (int*)ws;             ws += 64;                   // 8 queue tickets
    unsigned short* csrf    = (unsigned short*)ws;  ws += (size_t)N * CAP * 2;  // 6.4 MB u16 CSR
    _Float16*       y1s     = (_Float16*)ws;        ws += (size_t)N * 104 * 2;  // 10.4 MB
    _Float16*       h1s     = (_Float16*)ws;        ws += (size_t)N * 104 * 2;  // 10.4 MB
    _Float16*       g2h     = (_Float16*)ws;        ws += (size_t)N * 104 * 2;  // 10.4 MB
    _Float16*       h2      = y1s;  // overlay: y1s+h1s dead before gemm2; h2 = 2 planes x N*104

    hipMemsetAsync(cnt, 0, (size_t)N * 4 + 64, stream);  // cnt + tickets (contiguous)

    // CSR build: XCC-pinned work-stealing single pass
    const int CHUNK = 3200;                        // edges per ticket
    const int NCHUNK = (E + CHUNK - 1) / CHUNK;    // 250
    count_fill_kernel<<<2048, 256, 0, stream>>>(col, row, cnt, csrf, tickets, E, CHUNK, NCHUNK);

    const int GX = (N + 127) / 128;  // 391 row-blocks

    // Layer 1: y1s = f16((x@W1)*dis) ; h1s = f16(relu(dis*agg(y1s)+b1)*dis)
    gemm1_kernel<<<GX, 256, 0, stream>>>(x, W1, cnt, y1s, N);
    agg_h_kernel<true><<<N / 4, 256, 0, stream>>>((const __half2*)y1s, cnt, csrf, b1, (__half2*)h1s, N);

    // Layer 2: g2h = f16(dis*agg(h1s)) ; h2 = f16(relu(g2h@W2+b2)) in 2 col-planes
    agg_h_kernel<false><<<N / 4, 256, 0, stream>>>((const __half2*)h1s, cnt, csrf, nullptr, (__half2*)g2h, N);
    gemm2_kernel<<<dim3(GX, 2), 256, 0, stream>>>(g2h, W2, b2, h2, (size_t)N * 104, N);

    // out = h2 @ Wfc + bfc
    fc_h_kernel<<<(N * 4 + 255) / 256, 256, 0, stream>>>((const __half2*)h2, (size_t)N * 52, Wfc, bfc, out, N);
}

// Round 13
// 291.292 us; speedup vs baseline: 1.5999x; 1.5999x over previous
//
#include <hip/hip_runtime.h>
#include <hip/hip_fp16.h>

// Problem constants (match reference)
#define N_NODES 50000
#define N_EDGES 800000
#define F_IN 128
#define H1 100
#define H2 200
#define F_OUT 16
#define CAP 64  // fixed CSR slots/node: deg ~ Binom(800k,1/50k) = 16 +/- 4; P(>64) ~ 1e-20

typedef _Float16 f16x8 __attribute__((ext_vector_type(8)));
typedef _Float16 f16x4 __attribute__((ext_vector_type(4)));
typedef float f32x4 __attribute__((ext_vector_type(4)));

// ---------------- K1: heterogeneous grid = CSR build (blocks [0,ncf)) ----------------
// ----------------              + layer-1 MFMA GEMM (blocks [ncf,ncf+GX)) ------------
// CSR part: one random pass; rank = atomicAdd old value; cnt keeps TRUE degree.
// GEMM part: y1u[n][c] = (f16) sum_k x[n][k] W1[k][c]   (UNSCALED; dis deferred
// to agg1, which removes the cnt dependency and lets the two roles overlap:
// CF waves park on atomic latency while gemm waves issue MFMA - disjoint pipes).
// Frag maps (verified rounds 8-12): A row=lane&15,k=(lane>>4)*8+j;
// B col=lane&15 (from transposed Bs); D col=lane&15,row=(lane>>4)*4+reg.

__global__ __launch_bounds__(256) void build_gemm1_kernel(
        const int* __restrict__ col, const int* __restrict__ rowi,
        int* __restrict__ cnt, unsigned short* __restrict__ csrf,
        const float* __restrict__ A, const float* __restrict__ W,
        _Float16* __restrict__ out, int n_edges, int ncf, int n_rows) {
    constexpr int BM = 128, BK = 32, PIT = 40, K = F_IN, LDW = H1;
    __shared__ _Float16 As[BM * PIT];
    __shared__ _Float16 Bs[112 * PIT];

    if (blockIdx.x < ncf) {  // ---- CSR-build role (launched first = long pole) ----
        int e = blockIdx.x * 256 + threadIdx.x;
        if (e < n_edges) {
            int c = col[e];
            int r = atomicAdd(&cnt[c], 1);
            if (r < CAP) csrf[(size_t)c * CAP + r] = (unsigned short)rowi[e];
        }
        return;
    }

    // ---- GEMM role ----
    int tid = threadIdx.x;
    int w = tid >> 6, lane = tid & 63;
    int lrow = lane & 15, lk = lane >> 4;
    int m0 = (blockIdx.x - ncf) * BM;

    f32x4 acc[2][7];
#pragma unroll
    for (int m = 0; m < 2; ++m)
#pragma unroll
        for (int nf = 0; nf < 7; ++nf) acc[m][nf] = (f32x4){0.f, 0.f, 0.f, 0.f};

    for (int kc = 0; kc < K; kc += BK) {
        __syncthreads();
        for (int i = tid; i < BM * 8; i += 256) {
            int r = i >> 3, q = i & 7;
            float4 v = make_float4(0.f, 0.f, 0.f, 0.f);
            if (m0 + r < n_rows) v = *(const float4*)&A[(size_t)(m0 + r) * K + kc + q * 4];
            f16x4 h = {(_Float16)v.x, (_Float16)v.y, (_Float16)v.z, (_Float16)v.w};
            *(f16x4*)&As[r * PIT + q * 4] = h;
        }
        for (int i = tid; i < 112 * BK; i += 256) {
            int k = i / 112, c = i - k * 112;
            float v = (c < LDW) ? W[(size_t)(kc + k) * LDW + c] : 0.f;
            Bs[c * PIT + k] = (_Float16)v;
        }
        __syncthreads();
        f16x8 a0 = *(const f16x8*)&As[(w * 32 + lrow) * PIT + lk * 8];
        f16x8 a1 = *(const f16x8*)&As[(w * 32 + 16 + lrow) * PIT + lk * 8];
#pragma unroll
        for (int nf = 0; nf < 7; ++nf) {
            f16x8 b = *(const f16x8*)&Bs[(nf * 16 + lrow) * PIT + lk * 8];
            acc[0][nf] = __builtin_amdgcn_mfma_f32_16x16x32_f16(a0, b, acc[0][nf], 0, 0, 0);
            acc[1][nf] = __builtin_amdgcn_mfma_f32_16x16x32_f16(a1, b, acc[1][nf], 0, 0, 0);
        }
    }

#pragma unroll
    for (int m = 0; m < 2; ++m) {
        int rb = m0 + w * 32 + m * 16 + lk * 4;
#pragma unroll
        for (int r = 0; r < 4; ++r) {
            int grow = rb + r;
            if (grow >= n_rows) continue;
            size_t base = (size_t)grow * 104;
#pragma unroll
            for (int nf = 0; nf < 7; ++nf) {
                int c = nf * 16 + lrow;
                if (c < 100) out[base + c] = (_Float16)acc[m][nf][r];
            }
        }
    }
}

// ---------------- MFMA fp16 GEMM layer 2 (f16 input pitch 104), 2 col-planes ----
// h2[plane(by)][n][c] = (f16) relu( sum_k g2h[n][k] W2[k][col_off+c] + b2[col_off+c] )

__global__ __launch_bounds__(256) void gemm2_kernel(
        const _Float16* __restrict__ A, const float* __restrict__ W,
        const float* __restrict__ b2, _Float16* __restrict__ out,
        size_t planeH, int n_rows) {
    constexpr int BM = 128, BK = 32, PIT = 40, K = H1, LDW = H2;
    __shared__ _Float16 As[BM * PIT];
    __shared__ _Float16 Bs[112 * PIT];

    int tid = threadIdx.x;
    int w = tid >> 6, lane = tid & 63;
    int lrow = lane & 15, lk = lane >> 4;
    int m0 = blockIdx.x * BM;
    int col_off = blockIdx.y * 100;

    f32x4 acc[2][7];
#pragma unroll
    for (int m = 0; m < 2; ++m)
#pragma unroll
        for (int nf = 0; nf < 7; ++nf) acc[m][nf] = (f32x4){0.f, 0.f, 0.f, 0.f};

    for (int kc = 0; kc < K; kc += BK) {  // 0,32,64,96
        __syncthreads();
        for (int i = tid; i < BM * 8; i += 256) {
            int r = i >> 3, q = i & 7, kb = kc + q * 4;
            f16x4 h = {(_Float16)0.f, (_Float16)0.f, (_Float16)0.f, (_Float16)0.f};
            if (m0 + r < n_rows && kb < K)
                h = *(const f16x4*)&A[(size_t)(m0 + r) * 104 + kb];
            *(f16x4*)&As[r * PIT + q * 4] = h;
        }
        for (int i = tid; i < 112 * BK; i += 256) {
            int k = i / 112, c = i - k * 112;
            float v = (c < 100 && kc + k < K) ? W[(size_t)(kc + k) * LDW + col_off + c] : 0.f;
            Bs[c * PIT + k] = (_Float16)v;
        }
        __syncthreads();
        f16x8 a0 = *(const f16x8*)&As[(w * 32 + lrow) * PIT + lk * 8];
        f16x8 a1 = *(const f16x8*)&As[(w * 32 + 16 + lrow) * PIT + lk * 8];
#pragma unroll
        for (int nf = 0; nf < 7; ++nf) {
            f16x8 b = *(const f16x8*)&Bs[(nf * 16 + lrow) * PIT + lk * 8];
            acc[0][nf] = __builtin_amdgcn_mfma_f32_16x16x32_f16(a0, b, acc[0][nf], 0, 0, 0);
            acc[1][nf] = __builtin_amdgcn_mfma_f32_16x16x32_f16(a1, b, acc[1][nf], 0, 0, 0);
        }
    }

    _Float16* o = out + blockIdx.y * planeH;
    float bv[7];
#pragma unroll
    for (int nf = 0; nf < 7; ++nf) {
        int c = nf * 16 + lrow;
        bv[nf] = (c < 100) ? b2[col_off + c] : 0.f;
    }
#pragma unroll
    for (int m = 0; m < 2; ++m) {
        int rb = m0 + w * 32 + m * 16 + lk * 4;
#pragma unroll
        for (int r = 0; r < 4; ++r) {
            int grow = rb + r;
            if (grow >= n_rows) continue;
            size_t base = (size_t)grow * 104;
#pragma unroll
            for (int nf = 0; nf < 7; ++nf) {
                int c = nf * 16 + lrow;
                if (c < 100) o[base + c] = (_Float16)fmaxf(acc[m][nf][r] + bv[nf], 0.f);
            }
        }
    }
}

// ---------------- Aggregation over fp16 rows (pitch 52 half2, one wave/node) ----
// SCALE_SRC=true (agg1): sources are UNSCALED y1u; per-lane prefetch
//   dv=rsqrt(cnt[slot]+1), shfl alongside slot id, acc = sum d_s*y1u[s]
//   (incl. self d_n*y1u[n]); out = f16( relu(d_n*acc + b) * d_n ).
// SCALE_SRC=false (agg2): sources are final h1s; acc = plain sum;
//   out = f16( d_n*acc ).

template <bool SCALE_SRC>
__global__ void agg_h_kernel(const __half2* __restrict__ Y, const int* __restrict__ cnt,
                             const unsigned short* __restrict__ csrf,
                             const float* __restrict__ bias,
                             __half2* __restrict__ out, int n_nodes) {
    int wave = threadIdx.x >> 6, lane = threadIdx.x & 63;
    int n = blockIdx.x * 4 + wave;
    if (n >= n_nodes) return;
    bool act = lane < 50;
    int deg0 = cnt[n];
    int deg = min(deg0, CAP);
    float dn = rsqrtf((float)deg0 + 1.0f);

    float ax = 0.f, ay = 0.f;
    if (act) {
        float2 v = __half22float2(Y[(size_t)n * 52 + lane]);  // self-loop term
        float sc = SCALE_SRC ? dn : 1.0f;
        ax = sc * v.x; ay = sc * v.y;
    }
    const unsigned short* slots = csrf + (size_t)n * CAP;
    int my = (lane < deg) ? (int)slots[lane] : 0;  // one coalesced batch covers deg<=64
    float dv = 1.0f;
    if (SCALE_SRC) dv = rsqrtf((float)cnt[my] + 1.0f);  // per-source dis (L2-resident)

    int i = 0;
    for (; i + 8 <= deg; i += 8) {
        int s0 = __shfl(my, i),     s1 = __shfl(my, i + 1);
        int s2 = __shfl(my, i + 2), s3 = __shfl(my, i + 3);
        int s4 = __shfl(my, i + 4), s5 = __shfl(my, i + 5);
        int s6 = __shfl(my, i + 6), s7 = __shfl(my, i + 7);
        float d0 = 1.f, d1 = 1.f, d2 = 1.f, d3 = 1.f, d4 = 1.f, d5 = 1.f, d6 = 1.f, d7 = 1.f;
        if (SCALE_SRC) {
            d0 = __shfl(dv, i);     d1 = __shfl(dv, i + 1);
            d2 = __shfl(dv, i + 2); d3 = __shfl(dv, i + 3);
            d4 = __shfl(dv, i + 4); d5 = __shfl(dv, i + 5);
            d6 = __shfl(dv, i + 6); d7 = __shfl(dv, i + 7);
        }
        if (act) {
            float2 v0 = __half22float2(Y[(size_t)s0 * 52 + lane]);
            float2 v1 = __half22float2(Y[(size_t)s1 * 52 + lane]);
            float2 v2 = __half22float2(Y[(size_t)s2 * 52 + lane]);
            float2 v3 = __half22float2(Y[(size_t)s3 * 52 + lane]);
            float2 v4 = __half22float2(Y[(size_t)s4 * 52 + lane]);
            float2 v5 = __half22float2(Y[(size_t)s5 * 52 + lane]);
            float2 v6 = __half22float2(Y[(size_t)s6 * 52 + lane]);
            float2 v7 = __half22float2(Y[(size_t)s7 * 52 + lane]);
            if (SCALE_SRC) {
                ax = fmaf(d0, v0.x, fmaf(d1, v1.x, fmaf(d2, v2.x, fmaf(d3, v3.x, ax))));
                ax = fmaf(d4, v4.x, fmaf(d5, v5.x, fmaf(d6, v6.x, fmaf(d7, v7.x, ax))));
                ay = fmaf(d0, v0.y, fmaf(d1, v1.y, fmaf(d2, v2.y, fmaf(d3, v3.y, ay))));
                ay = fmaf(d4, v4.y, fmaf(d5, v5.y, fmaf(d6, v6.y, fmaf(d7, v7.y, ay))));
            } else {
                ax += ((v0.x + v1.x) + (v2.x + v3.x)) + ((v4.x + v5.x) + (v6.x + v7.x));
                ay += ((v0.y + v1.y) + (v2.y + v3.y)) + ((v4.y + v5.y) + (v6.y + v7.y));
            }
        }
    }
    for (; i < deg; ++i) {
        int s = __shfl(my, i);
        float ds = SCALE_SRC ? __shfl(dv, i) : 1.0f;
        if (act) {
            float2 v = __half22float2(Y[(size_t)s * 52 + lane]);
            if (SCALE_SRC) { ax = fmaf(ds, v.x, ax); ay = fmaf(ds, v.y, ay); }
            else           { ax += v.x; ay += v.y; }
        }
    }
    if (act) {
        float ox, oy;
        if (SCALE_SRC) {
            int f = lane * 2;
            ox = fmaxf(fmaf(ax, dn, bias[f]), 0.f) * dn;
            oy = fmaxf(fmaf(ay, dn, bias[f + 1]), 0.f) * dn;
        } else {
            ox = ax * dn;
            oy = ay * dn;
        }
        out[(size_t)n * 52 + lane] = __float22half2_rn(make_float2(ox, oy));
    }
}

// ---------------- Final FC from fp16 h2 col-planes ----------------
// out[n][c] = sum_p sum_k h2[p][n][k] * Wfc[p*100+k][c] + bfc[c]

__global__ void fc_h_kernel(const __half2* __restrict__ h2, size_t plane2,
                            const float* __restrict__ W, const float* __restrict__ b,
                            float* __restrict__ out, int n_rows) {
    int idx = blockIdx.x * blockDim.x + threadIdx.x;
    int n = idx >> 2;
    int cg = (idx & 3) * 4;
    if (n >= n_rows) return;
    float a0 = 0.f, a1 = 0.f, a2 = 0.f, a3 = 0.f;
#pragma unroll
    for (int p = 0; p < 2; ++p) {
        const __half2* hr = h2 + p * plane2 + (size_t)n * 52;
        const float* Wp = W + (size_t)(p * 100) * F_OUT + cg;
#pragma unroll 5
        for (int k2 = 0; k2 < 50; ++k2) {
            float2 hv = __half22float2(hr[k2]);
            float4 w0 = *(const float4*)&Wp[(2 * k2) * F_OUT];
            float4 w1 = *(const float4*)&Wp[(2 * k2 + 1) * F_OUT];
            a0 = fmaf(hv.x, w0.x, fmaf(hv.y, w1.x, a0));
            a1 = fmaf(hv.x, w0.y, fmaf(hv.y, w1.y, a1));
            a2 = fmaf(hv.x, w0.z, fmaf(hv.y, w1.z, a2));
            a3 = fmaf(hv.x, w0.w, fmaf(hv.y, w1.w, a3));
        }
    }
    float4 bv = *(const float4*)&b[cg];
    float4 o = {a0 + bv.x, a1 + bv.y, a2 + bv.z, a3 + bv.w};
    *(float4*)&out[(size_t)n * F_OUT + cg] = o;
}

// ---------------- Launch ----------------

extern "C" void kernel_launch(void* const* d_in, const int* in_sizes, int n_in,
                              void* d_out, int out_size, void* d_ws, size_t ws_size,
                              hipStream_t stream) {
    const float* x   = (const float*)d_in[0];
    const int*   ei  = (const int*)d_in[1];
    const float* W1  = (const float*)d_in[2];
    const float* b1  = (const float*)d_in[3];
    const float* W2  = (const float*)d_in[4];
    const float* b2  = (const float*)d_in[5];
    const float* Wfc = (const float*)d_in[6];
    const float* bfc = (const float*)d_in[7];
    float* out = (float*)d_out;

    const int N = N_NODES, E = N_EDGES;
    const int* row = ei;
    const int* col = ei + E;

    // Workspace (~38 MB, all 16B-aligned)
    char* ws = (char*)d_ws;
    int*            cnt  = (int*)ws;             ws += (size_t)N * 4;        // true in-degree
    unsigned short* csrf = (unsigned short*)ws;  ws += (size_t)N * CAP * 2;  // 6.4 MB u16 CSR
    _Float16*       y1u  = (_Float16*)ws;        ws += (size_t)N * 104 * 2;  // 10.4 MB (unscaled)
    _Float16*       h1s  = (_Float16*)ws;        ws += (size_t)N * 104 * 2;  // 10.4 MB
    _Float16*       g2h  = (_Float16*)ws;        ws += (size_t)N * 104 * 2;  // 10.4 MB
    _Float16*       h2   = y1u;  // overlay: y1u+h1s dead before gemm2; h2 = 2 planes x N*104

    hipMemsetAsync(cnt, 0, (size_t)N * 4, stream);

    const int NCF = (E + 255) / 256;  // 3125 CSR-build blocks
    const int GX = (N + 127) / 128;   // 391 gemm row-blocks

    // K1: CSR build (blocks [0,NCF)) overlapped with layer-1 GEMM (blocks [NCF,NCF+GX))
    build_gemm1_kernel<<<NCF + GX, 256, 0, stream>>>(col, row, cnt, csrf, x, W1, y1u, E, NCF, N);

    // agg1: h1s = f16(relu(dn*(sum d_s*y1u[s]) + b1)*dn)   (src-scaled gather)
    agg_h_kernel<true><<<N / 4, 256, 0, stream>>>((const __half2*)y1u, cnt, csrf, b1, (__half2*)h1s, N);

    // agg2: g2h = f16(dn*sum h1s[s])
    agg_h_kernel<false><<<N / 4, 256, 0, stream>>>((const __half2*)h1s, cnt, csrf, nullptr, (__half2*)g2h, N);

    // Layer 2 GEMM + final FC
    gemm2_kernel<<<dim3(GX, 2), 256, 0, stream>>>(g2h, W2, b2, h2, (size_t)N * 104, N);
    fc_h_kernel<<<(N * 4 + 255) / 256, 256, 0, stream>>>((const __half2*)h2, (size_t)N * 52, Wfc, bfc, out, N);
}